// Round 16
// baseline (190.401 us; speedup 1.0000x reference)
//
#include <hip/hip_runtime.h>
#include <hip/hip_bf16.h>

typedef __attribute__((ext_vector_type(8))) short short8;
typedef __attribute__((ext_vector_type(4))) float f32x4;
typedef unsigned short ushort_t;

__device__ __forceinline__ ushort_t f2bf(float f) {
    union { __hip_bfloat16 h; ushort_t u; } c;
    c.h = __float2bfloat16(f);
    return c.u;
}

__device__ __forceinline__ short8 cvt8(float4 a, float4 b) {
    short8 o;
    o[0] = (short)f2bf(a.x); o[1] = (short)f2bf(a.y);
    o[2] = (short)f2bf(a.z); o[3] = (short)f2bf(a.w);
    o[4] = (short)f2bf(b.x); o[5] = (short)f2bf(b.y);
    o[6] = (short)f2bf(b.z); o[7] = (short)f2bf(b.w);
    return o;
}

__device__ __forceinline__ void gload16(const ushort_t* g, ushort_t* l) {
    __builtin_amdgcn_global_load_lds(
        (const __attribute__((address_space(1))) void*)g,
        (__attribute__((address_space(3))) void*)l, 16, 0, 0);
}

// ---------------- prep ----------------
// z=0: transpose Wv fp32 -> bf16 Wvt[e][d]
// z=1: convert x fp32 -> bf16 xb
// z=2 (first 64 blocks): Mt = Wk . Wq^T bf16, reg-staged fp32 GEMM (R0 pattern)
//     (compute-bound; co-schedules with the BW-bound z=0/1 blocks)
__global__ __launch_bounds__(256) void k_prep(const float* __restrict__ x,
                                              const float* __restrict__ Wq,
                                              const float* __restrict__ Wk,
                                              const float* __restrict__ Wv,
                                              ushort_t* __restrict__ xb,
                                              ushort_t* __restrict__ Mt,
                                              ushort_t* __restrict__ Wvt) {
    __shared__ ushort_t sm[10240];   // 20480 B union: mm tiles / Wv tile
    const int bz = blockIdx.z;
    const int t = threadIdx.y * 32 + threadIdx.x;

    if (bz == 1) {
        // convert x: 1024 blocks x 256 thr x 8 elems x 4 passes
        size_t base = ((size_t)(blockIdx.y * 32 + blockIdx.x) * 256 + t) * 8;
#pragma unroll
        for (int p = 0; p < 4; ++p) {
            size_t idx = base + (size_t)p * 2097152;
            float4 a = *(const float4*)(x + idx);
            float4 b = *(const float4*)(x + idx + 4);
            *(short8*)(xb + idx) = cvt8(a, b);
        }
        return;
    }
    if (bz == 0) {
        // transpose Wv
        float* tile = (float*)sm;                      // [32][33]
        int tx = threadIdx.x, ty = threadIdx.y;        // 32 x 8
        int d0 = blockIdx.y * 32, e0 = blockIdx.x * 32;
#pragma unroll
        for (int i = 0; i < 32; i += 8)
            tile[(ty + i) * 33 + tx] = Wv[(size_t)(d0 + ty + i) * 1024 + e0 + tx];
        __syncthreads();
#pragma unroll
        for (int i = 0; i < 32; i += 8)
            Wvt[(size_t)(e0 + ty + i) * 1024 + d0 + tx] = f2bf(tile[tx * 33 + ty + i]);
        return;
    }
    // bz == 2: mm (only 8x8 blocks active)
    if (blockIdx.x >= 8 || blockIdx.y >= 8) return;
    const int bm = blockIdx.x, bn = blockIdx.y;
    ushort_t* As = sm;            // [128][40] padded
    ushort_t* Bs = sm + 5120;

    const int ar = t >> 1, ac = (t & 1) << 4;
    const int l = t & 63, wid = t >> 6;
    const int wr = (wid >> 1) * 64, wc = (wid & 1) * 64;
    const int lr = l & 15, kc = (l >> 4) * 8;

    f32x4 zero = {0.f, 0.f, 0.f, 0.f};
    f32x4 acc[4][4];
#pragma unroll
    for (int m = 0; m < 4; ++m)
#pragma unroll
        for (int n = 0; n < 4; ++n) acc[m][n] = zero;

    for (int ks = 0; ks < 32; ++ks) {
        const float* ap = Wk + (size_t)(bm * 128 + ar) * 1024 + ks * 32 + ac;
        const float* bp = Wq + (size_t)(bn * 128 + ar) * 1024 + ks * 32 + ac;
        short8 av0 = cvt8(*(const float4*)ap, *(const float4*)(ap + 4));
        short8 av1 = cvt8(*(const float4*)(ap + 8), *(const float4*)(ap + 12));
        short8 bv0 = cvt8(*(const float4*)bp, *(const float4*)(bp + 4));
        short8 bv1 = cvt8(*(const float4*)(bp + 8), *(const float4*)(bp + 12));
        __syncthreads();
        *(short8*)&As[ar * 40 + ac] = av0;
        *(short8*)&As[ar * 40 + ac + 8] = av1;
        *(short8*)&Bs[ar * 40 + ac] = bv0;
        *(short8*)&Bs[ar * 40 + ac + 8] = bv1;
        __syncthreads();

        short8 a[4], b[4];
#pragma unroll
        for (int m = 0; m < 4; ++m)
            a[m] = *(const short8*)&As[(wr + m * 16 + lr) * 40 + kc];
#pragma unroll
        for (int n = 0; n < 4; ++n)
            b[n] = *(const short8*)&Bs[(wc + n * 16 + lr) * 40 + kc];
#pragma unroll
        for (int m = 0; m < 4; ++m)
#pragma unroll
            for (int n = 0; n < 4; ++n)
                acc[m][n] = __builtin_amdgcn_mfma_f32_16x16x32_bf16(a[m], b[n], acc[m][n], 0, 0, 0);
    }

    const int rbase = (l >> 4) * 4;
    const int cbase = l & 15;
#pragma unroll
    for (int m = 0; m < 4; ++m)
#pragma unroll
        for (int n = 0; n < 4; ++n) {
            int gcol = bn * 128 + wc + n * 16 + cbase;
#pragma unroll
            for (int r = 0; r < 4; ++r) {
                int grow = bm * 128 + wr + m * 16 + rbase + r;
                Mt[(size_t)grow * 1024 + gcol] = f2bf(acc[m][n][r]);
            }
        }
}

// ---------------- proj GEMM (m97 128x128, simple loop — best at 4 blocks/CU)
// A=xb; bz=0: B=Mt -> y bf16; bz=1: B=Wvt -> Vt via LDS bounce
__global__ __launch_bounds__(256) void k_gemm(const ushort_t* __restrict__ Abase,
                                              const ushort_t* __restrict__ Bbase,
                                              void* __restrict__ Cbase,
                                              ushort_t* __restrict__ Vt) {
    const int bm = blockIdx.x, bn = blockIdx.y, bz = blockIdx.z;
    const ushort_t* A = Abase;
    const ushort_t* B = Bbase + (size_t)bz * 1048576;   // Mt then Wvt (adjacent)
    const int lda = 1024, ldb = 1024, nk = 32;

    __shared__ ushort_t smem[128 * 130];
    ushort_t* As = smem;          // [128][32] linear (gload_lds dest)
    ushort_t* Bs = smem + 4096;

    const int tid = threadIdx.x;
    const int l = tid & 63, wid = tid >> 6;
    const int wr = (wid >> 1) * 64, wc = (wid & 1) * 64;
    const int lr = l & 15, kc = (l >> 4) * 8;

    const int srow = tid >> 2, skb = (tid & 3) * 8;
    const ushort_t* ag = A + (size_t)(bm * 128 + srow) * lda + skb;
    const ushort_t* bg = B + (size_t)(bn * 128 + srow) * ldb + skb;
    const size_t a64 = (size_t)64 * lda, b64 = (size_t)64 * ldb;
    ushort_t* al = As + tid * 8;
    ushort_t* bl = Bs + tid * 8;

    f32x4 zero = {0.f, 0.f, 0.f, 0.f};
    f32x4 acc[4][4];
#pragma unroll
    for (int m = 0; m < 4; ++m)
#pragma unroll
        for (int n = 0; n < 4; ++n) acc[m][n] = zero;

    for (int ks = 0; ks < nk; ++ks) {
        __syncthreads();
        gload16(ag, al);
        gload16(ag + a64, al + 2048);
        gload16(bg, bl);
        gload16(bg + b64, bl + 2048);
        ag += 32; bg += 32;
        __syncthreads();

        short8 a[4], b[4];
#pragma unroll
        for (int m = 0; m < 4; ++m)
            a[m] = *(const short8*)&As[(wr + m * 16 + lr) * 32 + kc];
#pragma unroll
        for (int n = 0; n < 4; ++n)
            b[n] = *(const short8*)&Bs[(wc + n * 16 + lr) * 32 + kc];
#pragma unroll
        for (int m = 0; m < 4; ++m)
#pragma unroll
            for (int n = 0; n < 4; ++n)
                acc[m][n] = __builtin_amdgcn_mfma_f32_16x16x32_bf16(a[m], b[n], acc[m][n], 0, 0, 0);
    }

    const int rbase = (l >> 4) * 4;
    const int cbase = l & 15;

    if (bz == 1) {
        // V tile: transpose via LDS bounce [128][130], write Vt[b][e][j]
        __syncthreads();
#pragma unroll
        for (int m = 0; m < 4; ++m)
#pragma unroll
            for (int n = 0; n < 4; ++n) {
                int col = wc + n * 16 + cbase;
                int row0 = wr + m * 16 + rbase;
#pragma unroll
                for (int r = 0; r < 4; ++r)
                    smem[col * 130 + row0 + r] = f2bf(acc[m][n][r]);
            }
        __syncthreads();
        const int e = tid >> 1, jh = (tid & 1) * 64;
        const int b = bm >> 4, j0 = (bm * 128) & 2047;
        ushort_t* dst = Vt + (size_t)b * 2097152 +
                        (size_t)(bn * 128 + e) * 2048 + j0 + jh;
        const ushort_t* src = smem + e * 130 + jh;
#pragma unroll
        for (int c = 0; c < 8; ++c)
            *(short8*)(dst + c * 8) = *(const short8*)(src + c * 8);
        return;
    }

#pragma unroll
    for (int m = 0; m < 4; ++m) {
#pragma unroll
        for (int n = 0; n < 4; ++n) {
            int col = wc + n * 16 + cbase;
            int gcol = bn * 128 + col;
#pragma unroll
            for (int r = 0; r < 4; ++r) {
                int grow = bm * 128 + wr + m * 16 + rbase + r;
                ushort_t* C = (ushort_t*)Cbase;
                C[(size_t)grow * 1024 + gcol] = f2bf(acc[m][n][r]);
            }
        }
    }
}

// ---------------- attn GEMMs (128x128, stage-ahead double-buffer) -----------
// MODE 1: qk  triangular (136,1,4): P' = exp(s/32) bf16, causal-masked 0
// MODE 2: pv  (16,8,4): A=P' lda=2048; B=Vt; rowsum via ones-MFMA; out=acc/rs
//             bm complemented on z>=2 so co-resident pairs (L, L+256) sum to
//             constant work.
template <int MODE>
__global__ __launch_bounds__(256) void k_attn(const ushort_t* __restrict__ Abase,
                                              const ushort_t* __restrict__ Bbase,
                                              void* __restrict__ Cbase) {
    int bm, bn;
    const int bz = blockIdx.z;
    const ushort_t* A;
    const ushort_t* B;
    int lda, ldb, nk;
    if constexpr (MODE == 1) {
        int x = blockIdx.x;
        bm = (int)((sqrtf(8.f * x + 1.f) - 1.f) * 0.5f);
        while ((bm + 1) * (bm + 2) / 2 <= x) ++bm;
        while (bm * (bm + 1) / 2 > x) --bm;
        bn = x - bm * (bm + 1) / 2;
        A = Abase + (size_t)bz * 2048 * 1024; lda = 1024;
        B = Bbase + (size_t)bz * 2048 * 1024; ldb = 1024;
        nk = 32;
    } else {
        int xr = blockIdx.x;                       // heavy/light interleave
        int m0 = (xr & 1) ? (15 - (xr >> 1)) : (xr >> 1);
        bm = (bz & 2) ? (15 - m0) : m0;            // complement on z-half
        bn = blockIdx.y;
        A = Abase + (size_t)bz * 2048 * 2048; lda = 2048;
        B = Bbase + (size_t)bz * 1024 * 2048; ldb = 2048;
        nk = (bm + 1) * 4;
    }

    __shared__ ushort_t As[2][4096];   // [dbuf][128*32]  16KB
    __shared__ ushort_t Bs[2][4096];   // 16KB

    const int tid = threadIdx.x;
    const int l = tid & 63, wid = tid >> 6;
    const int wr = (wid >> 1) * 64, wc = (wid & 1) * 64;
    const int lr = l & 15, kc = (l >> 4) * 8;

    const int srow = tid >> 2, skb = (tid & 3) * 8;
    const ushort_t* ag = A + (size_t)(bm * 128 + srow) * lda + skb;
    const ushort_t* bg = B + (size_t)(bn * 128 + srow) * ldb + skb;
    const size_t a64 = (size_t)64 * lda, b64 = (size_t)64 * ldb;

    f32x4 zero = {0.f, 0.f, 0.f, 0.f};
    f32x4 acc[4][4];
#pragma unroll
    for (int m = 0; m < 4; ++m)
#pragma unroll
        for (int n = 0; n < 4; ++n) acc[m][n] = zero;

    f32x4 rs[4];            // MODE 2 rowsums
    short8 ones;
#pragma unroll
    for (int e = 0; e < 8; ++e) ones[e] = (short)0x3F80;   // bf16 1.0
#pragma unroll
    for (int m = 0; m < 4; ++m) rs[m] = zero;

    // prologue: stage ks=0 into buf 0
    gload16(ag, &As[0][tid * 8]);
    gload16(ag + a64, &As[0][tid * 8 + 2048]);
    gload16(bg, &Bs[0][tid * 8]);
    gload16(bg + b64, &Bs[0][tid * 8 + 2048]);
    ag += 32; bg += 32;
    __syncthreads();   // drains vmcnt -> buf0 visible

    int cur = 0;
    for (int ks = 0; ks < nk; ++ks) {
        // stage-ahead: issue next tile's loads first (fly under compute)
        if (ks + 1 < nk) {
            const int nxt = cur ^ 1;
            gload16(ag, &As[nxt][tid * 8]);
            gload16(ag + a64, &As[nxt][tid * 8 + 2048]);
            gload16(bg, &Bs[nxt][tid * 8]);
            gload16(bg + b64, &Bs[nxt][tid * 8 + 2048]);
            ag += 32; bg += 32;
        }

        short8 a[4], b[4];
#pragma unroll
        for (int m = 0; m < 4; ++m)
            a[m] = *(const short8*)&As[cur][(wr + m * 16 + lr) * 32 + kc];
#pragma unroll
        for (int n = 0; n < 4; ++n)
            b[n] = *(const short8*)&Bs[cur][(wc + n * 16 + lr) * 32 + kc];
#pragma unroll
        for (int m = 0; m < 4; ++m)
#pragma unroll
            for (int n = 0; n < 4; ++n)
                acc[m][n] = __builtin_amdgcn_mfma_f32_16x16x32_bf16(a[m], b[n], acc[m][n], 0, 0, 0);
        if constexpr (MODE == 2) {
#pragma unroll
            for (int m = 0; m < 4; ++m)
                rs[m] = __builtin_amdgcn_mfma_f32_16x16x32_bf16(a[m], ones, rs[m], 0, 0, 0);
        }

        __syncthreads();   // drains vmcnt (next buf staged) + seals cur reads
        cur ^= 1;
    }

    const int rbase = (l >> 4) * 4;
    const int cbase = l & 15;

    if constexpr (MODE == 1) {
        ushort_t* C = (ushort_t*)Cbase + (size_t)bz * 2048 * 2048;
#pragma unroll
        for (int m = 0; m < 4; ++m)
#pragma unroll
            for (int n = 0; n < 4; ++n) {
                int gcol = bn * 128 + wc + n * 16 + cbase;
#pragma unroll
                for (int r = 0; r < 4; ++r) {
                    int grow = bm * 128 + wr + m * 16 + rbase + r;
                    ushort_t pv = (gcol <= grow) ? f2bf(__expf(acc[m][n][r] * 0.03125f))
                                                 : (ushort_t)0;
                    C[(size_t)grow * 2048 + gcol] = pv;
                }
            }
    } else {
        float inv[4][4];
#pragma unroll
        for (int m = 0; m < 4; ++m)
#pragma unroll
            for (int r = 0; r < 4; ++r) inv[m][r] = 1.0f / rs[m][r];
        float* C = (float*)Cbase + (size_t)bz * 2048 * 1024;
#pragma unroll
        for (int m = 0; m < 4; ++m)
#pragma unroll
            for (int n = 0; n < 4; ++n) {
                int gcol = bn * 128 + wc + n * 16 + cbase;
#pragma unroll
                for (int r = 0; r < 4; ++r) {
                    int grow = bm * 128 + wr + m * 16 + rbase + r;
                    C[(size_t)grow * 1024 + gcol] = acc[m][n][r] * inv[m][r];
                }
            }
    }
}

extern "C" void kernel_launch(void* const* d_in, const int* in_sizes, int n_in,
                              void* d_out, int out_size, void* d_ws, size_t ws_size,
                              hipStream_t stream) {
    const float* x  = (const float*)d_in[0];
    const float* Wq = (const float*)d_in[1];
    const float* Wk = (const float*)d_in[2];
    const float* Wv = (const float*)d_in[3];

    char* ws = (char*)d_ws;
    ushort_t* xb  = (ushort_t*)(ws);                 // 16 MB [8192][1024]
    ushort_t* Mt  = (ushort_t*)(ws + 16777216);      // 2 MB [e][d] = (Wq.Wk^T)^T
    ushort_t* Wvt = (ushort_t*)(ws + 18874368);      // 2 MB (adjacent to Mt)
    ushort_t* y   = (ushort_t*)(ws + 20971520);      // 16 MB [8192][1024] = x.M
    ushort_t* Vt  = (ushort_t*)(ws + 37748736);      // 16 MB [4][1024][2048]
    ushort_t* P   = (ushort_t*)(ws + 54525952);      // 32 MB [4][2048][2048] bf16

    k_prep<<<dim3(32, 32, 3), dim3(32, 8), 0, stream>>>(x, Wq, Wk, Wv, xb, Mt, Wvt);
    k_gemm<<<dim3(64, 8, 2), 256, 0, stream>>>(xb, Mt, y, Vt);
    k_attn<1><<<dim3(136, 1, 4), 256, 0, stream>>>(y, xb, P);
    k_attn<2><<<dim3(16, 8, 4), 256, 0, stream>>>(P, Vt, (float*)d_out);
}

// Round 17
// 174.485 us; speedup vs baseline: 1.0912x; 1.0912x over previous
//
#include <hip/hip_runtime.h>
#include <hip/hip_bf16.h>

typedef __attribute__((ext_vector_type(8))) short short8;
typedef __attribute__((ext_vector_type(4))) short short4_t;
typedef __attribute__((ext_vector_type(4))) float f32x4;
typedef unsigned short ushort_t;

__device__ __forceinline__ ushort_t f2bf(float f) {
    union { __hip_bfloat16 h; ushort_t u; } c;
    c.h = __float2bfloat16(f);
    return c.u;
}

__device__ __forceinline__ void gload16(const ushort_t* g, ushort_t* l) {
    __builtin_amdgcn_global_load_lds(
        (const __attribute__((address_space(1))) void*)g,
        (__attribute__((address_space(3))) void*)l, 16, 0, 0);
}

// ---------------- prep ----------------
// z=0: convert Wq fp32 -> bf16; z=1: convert Wk; z=2: transpose Wv -> Wvt;
// z=3: convert x -> xb
__global__ __launch_bounds__(256) void k_prep(const float* __restrict__ x,
                                              const float* __restrict__ Wq,
                                              const float* __restrict__ Wk,
                                              const float* __restrict__ Wv,
                                              ushort_t* __restrict__ xb,
                                              ushort_t* __restrict__ Wqb,
                                              ushort_t* __restrict__ Wkb,
                                              ushort_t* __restrict__ Wvt) {
    const int bz = blockIdx.z;
    const int t = threadIdx.y * 32 + threadIdx.x;
    if (bz == 3) {
        size_t base = ((size_t)(blockIdx.y * 32 + blockIdx.x) * 256 + t) * 8;
#pragma unroll
        for (int p = 0; p < 4; ++p) {
            size_t idx = base + (size_t)p * 2097152;
            float4 a = *(const float4*)(x + idx);
            float4 b = *(const float4*)(x + idx + 4);
            short8 o;
            o[0] = (short)f2bf(a.x); o[1] = (short)f2bf(a.y);
            o[2] = (short)f2bf(a.z); o[3] = (short)f2bf(a.w);
            o[4] = (short)f2bf(b.x); o[5] = (short)f2bf(b.y);
            o[6] = (short)f2bf(b.z); o[7] = (short)f2bf(b.w);
            *(short8*)(xb + idx) = o;
        }
        return;
    }
    if (bz < 2) {
        const float* src = bz ? Wk : Wq;
        ushort_t* dst = bz ? Wkb : Wqb;
        size_t idx = ((size_t)(blockIdx.y * 32 + blockIdx.x) * 256 + t) * 4;
        float4 a = *(const float4*)(src + idx);
        short4_t o;
        o[0] = (short)f2bf(a.x); o[1] = (short)f2bf(a.y);
        o[2] = (short)f2bf(a.z); o[3] = (short)f2bf(a.w);
        *(short4_t*)(dst + idx) = o;
        return;
    }
    __shared__ float tile[32][33];
    int tx = threadIdx.x, ty = threadIdx.y;            // 32 x 8
    int d0 = blockIdx.y * 32, e0 = blockIdx.x * 32;
#pragma unroll
    for (int i = 0; i < 32; i += 8)
        tile[ty + i][tx] = Wv[(size_t)(d0 + ty + i) * 1024 + e0 + tx];
    __syncthreads();
#pragma unroll
    for (int i = 0; i < 32; i += 8)
        Wvt[(size_t)(e0 + ty + i) * 1024 + d0 + tx] = f2bf(tile[tx][ty + i]);
}

// ---------------- proj GEMM (m97 128x128, simple loop — best at 4 blocks/CU)
// A=xb; bz=0: B=Mt -> y bf16; bz=1: B=Wvt -> Vt via LDS bounce
__global__ __launch_bounds__(256) void k_gemm(const ushort_t* __restrict__ Abase,
                                              const ushort_t* __restrict__ Bbase,
                                              void* __restrict__ Cbase,
                                              ushort_t* __restrict__ Vt) {
    const int bm = blockIdx.x, bn = blockIdx.y, bz = blockIdx.z;
    const ushort_t* A = Abase;
    const ushort_t* B = Bbase + (size_t)bz * 1048576;   // Mt then Wvt (adjacent)
    const int lda = 1024, ldb = 1024, nk = 32;

    __shared__ ushort_t smem[128 * 130];
    ushort_t* As = smem;          // [128][32] linear (gload_lds dest)
    ushort_t* Bs = smem + 4096;

    const int tid = threadIdx.x;
    const int l = tid & 63, wid = tid >> 6;
    const int wr = (wid >> 1) * 64, wc = (wid & 1) * 64;
    const int lr = l & 15, kc = (l >> 4) * 8;

    const int srow = tid >> 2, skb = (tid & 3) * 8;
    const ushort_t* ag = A + (size_t)(bm * 128 + srow) * lda + skb;
    const ushort_t* bg = B + (size_t)(bn * 128 + srow) * ldb + skb;
    const size_t a64 = (size_t)64 * lda, b64 = (size_t)64 * ldb;
    ushort_t* al = As + tid * 8;
    ushort_t* bl = Bs + tid * 8;

    f32x4 zero = {0.f, 0.f, 0.f, 0.f};
    f32x4 acc[4][4];
#pragma unroll
    for (int m = 0; m < 4; ++m)
#pragma unroll
        for (int n = 0; n < 4; ++n) acc[m][n] = zero;

    for (int ks = 0; ks < nk; ++ks) {
        __syncthreads();
        gload16(ag, al);
        gload16(ag + a64, al + 2048);
        gload16(bg, bl);
        gload16(bg + b64, bl + 2048);
        ag += 32; bg += 32;
        __syncthreads();

        short8 a[4], b[4];
#pragma unroll
        for (int m = 0; m < 4; ++m)
            a[m] = *(const short8*)&As[(wr + m * 16 + lr) * 32 + kc];
#pragma unroll
        for (int n = 0; n < 4; ++n)
            b[n] = *(const short8*)&Bs[(wc + n * 16 + lr) * 32 + kc];
#pragma unroll
        for (int m = 0; m < 4; ++m)
#pragma unroll
            for (int n = 0; n < 4; ++n)
                acc[m][n] = __builtin_amdgcn_mfma_f32_16x16x32_bf16(a[m], b[n], acc[m][n], 0, 0, 0);
    }

    const int rbase = (l >> 4) * 4;
    const int cbase = l & 15;

    if (bz == 1) {
        // V tile: transpose via LDS bounce [128][130], write Vt[b][e][j]
        __syncthreads();
#pragma unroll
        for (int m = 0; m < 4; ++m)
#pragma unroll
            for (int n = 0; n < 4; ++n) {
                int col = wc + n * 16 + cbase;
                int row0 = wr + m * 16 + rbase;
#pragma unroll
                for (int r = 0; r < 4; ++r)
                    smem[col * 130 + row0 + r] = f2bf(acc[m][n][r]);
            }
        __syncthreads();
        const int e = tid >> 1, jh = (tid & 1) * 64;
        const int b = bm >> 4, j0 = (bm * 128) & 2047;
        ushort_t* dst = Vt + (size_t)b * 2097152 +
                        (size_t)(bn * 128 + e) * 2048 + j0 + jh;
        const ushort_t* src = smem + e * 130 + jh;
#pragma unroll
        for (int c = 0; c < 8; ++c)
            *(short8*)(dst + c * 8) = *(const short8*)(src + c * 8);
        return;
    }

#pragma unroll
    for (int m = 0; m < 4; ++m) {
#pragma unroll
        for (int n = 0; n < 4; ++n) {
            int col = wc + n * 16 + cbase;
            int gcol = bn * 128 + col;
#pragma unroll
            for (int r = 0; r < 4; ++r) {
                int grow = bm * 128 + wr + m * 16 + rbase + r;
                ushort_t* C = (ushort_t*)Cbase;
                C[(size_t)grow * 1024 + gcol] = f2bf(acc[m][n][r]);
            }
        }
    }
}

// ---------------- attn/mm GEMMs (128x128, stage-ahead double-buffer) --------
// Low-occupancy grids: issue next K-step's gloads BEFORE the current
// frag-reads+MFMA so global latency hides under compute.
// MODE 1: qk  triangular (136,1,4): P' = exp(s/32) bf16, causal-masked 0
// MODE 2: pv  (16,8,4): A=P' lda=2048; B=Vt; rowsum via ones-MFMA; out=acc/rs
//             bm complemented on z>=2 so co-resident pairs sum to const work
// MODE 3: mm  (8,8,1): Mt = Wkb . Wqb^T -> bf16 (0.25 blocks/CU — the purest
//             stage-ahead regime)
template <int MODE>
__global__ __launch_bounds__(256) void k_attn(const ushort_t* __restrict__ Abase,
                                              const ushort_t* __restrict__ Bbase,
                                              void* __restrict__ Cbase) {
    int bm, bn;
    const int bz = blockIdx.z;
    const ushort_t* A;
    const ushort_t* B;
    int lda, ldb, nk;
    if constexpr (MODE == 1) {
        int x = blockIdx.x;
        bm = (int)((sqrtf(8.f * x + 1.f) - 1.f) * 0.5f);
        while ((bm + 1) * (bm + 2) / 2 <= x) ++bm;
        while (bm * (bm + 1) / 2 > x) --bm;
        bn = x - bm * (bm + 1) / 2;
        A = Abase + (size_t)bz * 2048 * 1024; lda = 1024;
        B = Bbase + (size_t)bz * 2048 * 1024; ldb = 1024;
        nk = 32;
    } else if constexpr (MODE == 2) {
        int xr = blockIdx.x;                       // heavy/light interleave
        int m0 = (xr & 1) ? (15 - (xr >> 1)) : (xr >> 1);
        bm = (bz & 2) ? (15 - m0) : m0;            // complement on z-half
        bn = blockIdx.y;
        A = Abase + (size_t)bz * 2048 * 2048; lda = 2048;
        B = Bbase + (size_t)bz * 1024 * 2048; ldb = 2048;
        nk = (bm + 1) * 4;
    } else {
        bm = blockIdx.x; bn = blockIdx.y;
        A = Abase; lda = 1024;
        B = Bbase; ldb = 1024;
        nk = 32;
    }

    __shared__ ushort_t As[2][4096];   // [dbuf][128*32]  16KB
    __shared__ ushort_t Bs[2][4096];   // 16KB

    const int tid = threadIdx.x;
    const int l = tid & 63, wid = tid >> 6;
    const int wr = (wid >> 1) * 64, wc = (wid & 1) * 64;
    const int lr = l & 15, kc = (l >> 4) * 8;

    const int srow = tid >> 2, skb = (tid & 3) * 8;
    const ushort_t* ag = A + (size_t)(bm * 128 + srow) * lda + skb;
    const ushort_t* bg = B + (size_t)(bn * 128 + srow) * ldb + skb;
    const size_t a64 = (size_t)64 * lda, b64 = (size_t)64 * ldb;

    f32x4 zero = {0.f, 0.f, 0.f, 0.f};
    f32x4 acc[4][4];
#pragma unroll
    for (int m = 0; m < 4; ++m)
#pragma unroll
        for (int n = 0; n < 4; ++n) acc[m][n] = zero;

    f32x4 rs[4];            // MODE 2 rowsums
    short8 ones;
#pragma unroll
    for (int e = 0; e < 8; ++e) ones[e] = (short)0x3F80;   // bf16 1.0
#pragma unroll
    for (int m = 0; m < 4; ++m) rs[m] = zero;

    // prologue: stage ks=0 into buf 0
    gload16(ag, &As[0][tid * 8]);
    gload16(ag + a64, &As[0][tid * 8 + 2048]);
    gload16(bg, &Bs[0][tid * 8]);
    gload16(bg + b64, &Bs[0][tid * 8 + 2048]);
    ag += 32; bg += 32;
    __syncthreads();   // drains vmcnt -> buf0 visible

    int cur = 0;
    for (int ks = 0; ks < nk; ++ks) {
        // stage-ahead: issue next tile's loads first (fly under compute)
        if (ks + 1 < nk) {
            const int nxt = cur ^ 1;
            gload16(ag, &As[nxt][tid * 8]);
            gload16(ag + a64, &As[nxt][tid * 8 + 2048]);
            gload16(bg, &Bs[nxt][tid * 8]);
            gload16(bg + b64, &Bs[nxt][tid * 8 + 2048]);
            ag += 32; bg += 32;
        }

        short8 a[4], b[4];
#pragma unroll
        for (int m = 0; m < 4; ++m)
            a[m] = *(const short8*)&As[cur][(wr + m * 16 + lr) * 32 + kc];
#pragma unroll
        for (int n = 0; n < 4; ++n)
            b[n] = *(const short8*)&Bs[cur][(wc + n * 16 + lr) * 32 + kc];
#pragma unroll
        for (int m = 0; m < 4; ++m)
#pragma unroll
            for (int n = 0; n < 4; ++n)
                acc[m][n] = __builtin_amdgcn_mfma_f32_16x16x32_bf16(a[m], b[n], acc[m][n], 0, 0, 0);
        if constexpr (MODE == 2) {
#pragma unroll
            for (int m = 0; m < 4; ++m)
                rs[m] = __builtin_amdgcn_mfma_f32_16x16x32_bf16(a[m], ones, rs[m], 0, 0, 0);
        }

        __syncthreads();   // drains vmcnt (next buf staged) + seals cur reads
        cur ^= 1;
    }

    const int rbase = (l >> 4) * 4;
    const int cbase = l & 15;

    if constexpr (MODE == 1) {
        ushort_t* C = (ushort_t*)Cbase + (size_t)bz * 2048 * 2048;
#pragma unroll
        for (int m = 0; m < 4; ++m)
#pragma unroll
            for (int n = 0; n < 4; ++n) {
                int gcol = bn * 128 + wc + n * 16 + cbase;
#pragma unroll
                for (int r = 0; r < 4; ++r) {
                    int grow = bm * 128 + wr + m * 16 + rbase + r;
                    ushort_t pv = (gcol <= grow) ? f2bf(__expf(acc[m][n][r] * 0.03125f))
                                                 : (ushort_t)0;
                    C[(size_t)grow * 2048 + gcol] = pv;
                }
            }
    } else if constexpr (MODE == 2) {
        float inv[4][4];
#pragma unroll
        for (int m = 0; m < 4; ++m)
#pragma unroll
            for (int r = 0; r < 4; ++r) inv[m][r] = 1.0f / rs[m][r];
        float* C = (float*)Cbase + (size_t)bz * 2048 * 1024;
#pragma unroll
        for (int m = 0; m < 4; ++m)
#pragma unroll
            for (int n = 0; n < 4; ++n) {
                int gcol = bn * 128 + wc + n * 16 + cbase;
#pragma unroll
                for (int r = 0; r < 4; ++r) {
                    int grow = bm * 128 + wr + m * 16 + rbase + r;
                    C[(size_t)grow * 1024 + gcol] = acc[m][n][r] * inv[m][r];
                }
            }
    } else {
        ushort_t* C = (ushort_t*)Cbase;
#pragma unroll
        for (int m = 0; m < 4; ++m)
#pragma unroll
            for (int n = 0; n < 4; ++n) {
                int gcol = bn * 128 + wc + n * 16 + cbase;
#pragma unroll
                for (int r = 0; r < 4; ++r) {
                    int grow = bm * 128 + wr + m * 16 + rbase + r;
                    C[(size_t)grow * 1024 + gcol] = f2bf(acc[m][n][r]);
                }
            }
    }
}

extern "C" void kernel_launch(void* const* d_in, const int* in_sizes, int n_in,
                              void* d_out, int out_size, void* d_ws, size_t ws_size,
                              hipStream_t stream) {
    const float* x  = (const float*)d_in[0];
    const float* Wq = (const float*)d_in[1];
    const float* Wk = (const float*)d_in[2];
    const float* Wv = (const float*)d_in[3];

    char* ws = (char*)d_ws;
    ushort_t* xb  = (ushort_t*)(ws);                 // 16 MB [8192][1024]
    ushort_t* Wqb = (ushort_t*)(ws + 16777216);      // 2 MB
    ushort_t* Wkb = (ushort_t*)(ws + 18874368);      // 2 MB
    ushort_t* Mt  = (ushort_t*)(ws + 20971520);      // 2 MB [e][d] = (Wq.Wk^T)^T
    ushort_t* Wvt = (ushort_t*)(ws + 23068672);      // 2 MB (adjacent to Mt)
    ushort_t* y   = (ushort_t*)(ws + 25165824);      // 16 MB [8192][1024] = x.M
    ushort_t* Vt  = (ushort_t*)(ws + 41943040);      // 16 MB [4][1024][2048]
    ushort_t* P   = (ushort_t*)(ws + 58720256);      // 32 MB [4][2048][2048] bf16

    k_prep<<<dim3(32, 32, 4), dim3(32, 8), 0, stream>>>(x, Wq, Wk, Wv, xb, Wqb, Wkb, Wvt);
    k_attn<3><<<dim3(8, 8, 1), 256, 0, stream>>>(Wkb, Wqb, Mt);
    k_gemm<<<dim3(64, 8, 2), 256, 0, stream>>>(xb, Mt, y, Vt);
    k_attn<1><<<dim3(136, 1, 4), 256, 0, stream>>>(y, xb, P);
    k_attn<2><<<dim3(16, 8, 4), 256, 0, stream>>>(P, Vt, (float*)d_out);
}

// Round 18
// 169.803 us; speedup vs baseline: 1.1213x; 1.0276x over previous
//
#include <hip/hip_runtime.h>
#include <hip/hip_bf16.h>

typedef __attribute__((ext_vector_type(8))) short short8;
typedef __attribute__((ext_vector_type(4))) short short4_t;
typedef __attribute__((ext_vector_type(4))) float f32x4;
typedef unsigned short ushort_t;

__device__ __forceinline__ ushort_t f2bf(float f) {
    union { __hip_bfloat16 h; ushort_t u; } c;
    c.h = __float2bfloat16(f);
    return c.u;
}

__device__ __forceinline__ void gload16(const ushort_t* g, ushort_t* l) {
    __builtin_amdgcn_global_load_lds(
        (const __attribute__((address_space(1))) void*)g,
        (__attribute__((address_space(3))) void*)l, 16, 0, 0);
}

// ---------------- prep ----------------
// z=0: convert Wq fp32 -> bf16; z=1: convert Wk; z=2: transpose Wv -> Wvt;
// z=3: convert x -> xb
__global__ __launch_bounds__(256) void k_prep(const float* __restrict__ x,
                                              const float* __restrict__ Wq,
                                              const float* __restrict__ Wk,
                                              const float* __restrict__ Wv,
                                              ushort_t* __restrict__ xb,
                                              ushort_t* __restrict__ Wqb,
                                              ushort_t* __restrict__ Wkb,
                                              ushort_t* __restrict__ Wvt) {
    const int bz = blockIdx.z;
    const int t = threadIdx.y * 32 + threadIdx.x;
    if (bz == 3) {
        size_t base = ((size_t)(blockIdx.y * 32 + blockIdx.x) * 256 + t) * 8;
#pragma unroll
        for (int p = 0; p < 4; ++p) {
            size_t idx = base + (size_t)p * 2097152;
            float4 a = *(const float4*)(x + idx);
            float4 b = *(const float4*)(x + idx + 4);
            short8 o;
            o[0] = (short)f2bf(a.x); o[1] = (short)f2bf(a.y);
            o[2] = (short)f2bf(a.z); o[3] = (short)f2bf(a.w);
            o[4] = (short)f2bf(b.x); o[5] = (short)f2bf(b.y);
            o[6] = (short)f2bf(b.z); o[7] = (short)f2bf(b.w);
            *(short8*)(xb + idx) = o;
        }
        return;
    }
    if (bz < 2) {
        const float* src = bz ? Wk : Wq;
        ushort_t* dst = bz ? Wkb : Wqb;
        size_t idx = ((size_t)(blockIdx.y * 32 + blockIdx.x) * 256 + t) * 4;
        float4 a = *(const float4*)(src + idx);
        short4_t o;
        o[0] = (short)f2bf(a.x); o[1] = (short)f2bf(a.y);
        o[2] = (short)f2bf(a.z); o[3] = (short)f2bf(a.w);
        *(short4_t*)(dst + idx) = o;
        return;
    }
    __shared__ float tile[32][33];
    int tx = threadIdx.x, ty = threadIdx.y;            // 32 x 8
    int d0 = blockIdx.y * 32, e0 = blockIdx.x * 32;
#pragma unroll
    for (int i = 0; i < 32; i += 8)
        tile[ty + i][tx] = Wv[(size_t)(d0 + ty + i) * 1024 + e0 + tx];
    __syncthreads();
#pragma unroll
    for (int i = 0; i < 32; i += 8)
        Wvt[(size_t)(e0 + ty + i) * 1024 + d0 + tx] = f2bf(tile[tx][ty + i]);
}

// ---------------- GEMM (m97 128x128, simple loop — best at >=4 blocks/CU) ---
// MODE 3: mm    Mt[e][d] = Wkb . Wqb^T  (64 blocks)
// MODE 0: proj  A=xb; bz=0: B=Mt -> y bf16; bz=1: B=Wvt -> Vt via two-half
//               LDS bounce [64][130] (16.6KB union -> 6 blocks/CU vs 4)
template <int MODE>
__global__ __launch_bounds__(256) void k_gemm(const ushort_t* __restrict__ Abase,
                                              const ushort_t* __restrict__ Bbase,
                                              void* __restrict__ Cbase,
                                              ushort_t* __restrict__ Vt) {
    int bm, bn, bz;
    const ushort_t* A;
    const ushort_t* B;
    if constexpr (MODE == 3) {
        bm = blockIdx.x; bn = blockIdx.y; bz = 0;
        A = Abase; B = Bbase;
    } else {
        bm = blockIdx.x; bn = blockIdx.y; bz = blockIdx.z;
        A = Abase;
        B = Bbase + (size_t)bz * 1048576;   // Mt then Wvt (adjacent)
    }
    const int lda = 1024, ldb = 1024, nk = 32;

    constexpr int SMEM_ELEMS = (MODE == 0) ? (64 * 130) : 8192;  // 16640B / 16KB
    __shared__ ushort_t smem[SMEM_ELEMS];
    ushort_t* As = smem;          // [128][32] linear (gload_lds dest)
    ushort_t* Bs = smem + 4096;

    const int tid = threadIdx.x;
    const int l = tid & 63, wid = tid >> 6;
    const int wr = (wid >> 1) * 64, wc = (wid & 1) * 64;
    const int lr = l & 15, kc = (l >> 4) * 8;

    const int srow = tid >> 2, skb = (tid & 3) * 8;
    const ushort_t* ag = A + (size_t)(bm * 128 + srow) * lda + skb;
    const ushort_t* bg = B + (size_t)(bn * 128 + srow) * ldb + skb;
    const size_t a64 = (size_t)64 * lda, b64 = (size_t)64 * ldb;
    ushort_t* al = As + tid * 8;
    ushort_t* bl = Bs + tid * 8;

    f32x4 zero = {0.f, 0.f, 0.f, 0.f};
    f32x4 acc[4][4];
#pragma unroll
    for (int m = 0; m < 4; ++m)
#pragma unroll
        for (int n = 0; n < 4; ++n) acc[m][n] = zero;

    for (int ks = 0; ks < nk; ++ks) {
        __syncthreads();
        gload16(ag, al);
        gload16(ag + a64, al + 2048);
        gload16(bg, bl);
        gload16(bg + b64, bl + 2048);
        ag += 32; bg += 32;
        __syncthreads();

        short8 a[4], b[4];
#pragma unroll
        for (int m = 0; m < 4; ++m)
            a[m] = *(const short8*)&As[(wr + m * 16 + lr) * 32 + kc];
#pragma unroll
        for (int n = 0; n < 4; ++n)
            b[n] = *(const short8*)&Bs[(wc + n * 16 + lr) * 32 + kc];
#pragma unroll
        for (int m = 0; m < 4; ++m)
#pragma unroll
            for (int n = 0; n < 4; ++n)
                acc[m][n] = __builtin_amdgcn_mfma_f32_16x16x32_bf16(a[m], b[n], acc[m][n], 0, 0, 0);
    }

    const int rbase = (l >> 4) * 4;
    const int cbase = l & 15;

    if constexpr (MODE == 0) {
        if (bz == 1) {
            // V tile -> Vt[b][e][j], transposed via [64][130] bounce, 2 halves.
            // Waves with wc == h*64 own half h's columns (both row-blocks).
            const int b = bm >> 4, j0 = (bm * 128) & 2047;
#pragma unroll
            for (int h = 0; h < 2; ++h) {
                __syncthreads();   // staging (h=0) / previous copy (h=1) done
                if ((wid & 1) == h) {
#pragma unroll
                    for (int m = 0; m < 4; ++m)
#pragma unroll
                        for (int n = 0; n < 4; ++n) {
                            int col = n * 16 + cbase;         // 0..63 in half
                            int row0 = wr + m * 16 + rbase;
#pragma unroll
                            for (int r = 0; r < 4; ++r)
                                smem[col * 130 + row0 + r] = f2bf(acc[m][n][r]);
                        }
                }
                __syncthreads();
                const int c = tid >> 2, jq = (tid & 3) * 32;
                ushort_t* dst = Vt + (size_t)b * 2097152 +
                                (size_t)(bn * 128 + h * 64 + c) * 2048 + j0 + jq;
                const ushort_t* src = smem + c * 130 + jq;
#pragma unroll
                for (int q = 0; q < 4; ++q)
                    *(short8*)(dst + q * 8) = *(const short8*)(src + q * 8);
            }
            return;
        }
    }

#pragma unroll
    for (int m = 0; m < 4; ++m) {
#pragma unroll
        for (int n = 0; n < 4; ++n) {
            int col = wc + n * 16 + cbase;
            int gcol = bn * 128 + col;
#pragma unroll
            for (int r = 0; r < 4; ++r) {
                int grow = bm * 128 + wr + m * 16 + rbase + r;
                ushort_t* C = (ushort_t*)Cbase;
                C[(size_t)grow * 1024 + gcol] = f2bf(acc[m][n][r]);
            }
        }
    }
}

// ---------------- attn GEMMs (128x128, stage-ahead double-buffer) -----------
// MODE 1: qk  triangular (136,1,4): P' = exp(s/32) bf16, causal-masked 0
// MODE 2: pv  (16,8,4): A=P' lda=2048; B=Vt; rowsum via ones-MFMA; out=acc/rs
//             bm complemented on z>=2 so co-resident pairs sum to const work
template <int MODE>
__global__ __launch_bounds__(256) void k_attn(const ushort_t* __restrict__ Abase,
                                              const ushort_t* __restrict__ Bbase,
                                              void* __restrict__ Cbase) {
    int bm, bn;
    const int bz = blockIdx.z;
    const ushort_t* A;
    const ushort_t* B;
    int lda, ldb, nk;
    if constexpr (MODE == 1) {
        int x = blockIdx.x;
        bm = (int)((sqrtf(8.f * x + 1.f) - 1.f) * 0.5f);
        while ((bm + 1) * (bm + 2) / 2 <= x) ++bm;
        while (bm * (bm + 1) / 2 > x) --bm;
        bn = x - bm * (bm + 1) / 2;
        A = Abase + (size_t)bz * 2048 * 1024; lda = 1024;
        B = Bbase + (size_t)bz * 2048 * 1024; ldb = 1024;
        nk = 32;
    } else {
        int xr = blockIdx.x;                       // heavy/light interleave
        int m0 = (xr & 1) ? (15 - (xr >> 1)) : (xr >> 1);
        bm = (bz & 2) ? (15 - m0) : m0;            // complement on z-half
        bn = blockIdx.y;
        A = Abase + (size_t)bz * 2048 * 2048; lda = 2048;
        B = Bbase + (size_t)bz * 1024 * 2048; ldb = 2048;
        nk = (bm + 1) * 4;
    }

    __shared__ ushort_t As[2][4096];   // [dbuf][128*32]  16KB
    __shared__ ushort_t Bs[2][4096];   // 16KB

    const int tid = threadIdx.x;
    const int l = tid & 63, wid = tid >> 6;
    const int wr = (wid >> 1) * 64, wc = (wid & 1) * 64;
    const int lr = l & 15, kc = (l >> 4) * 8;

    const int srow = tid >> 2, skb = (tid & 3) * 8;
    const ushort_t* ag = A + (size_t)(bm * 128 + srow) * lda + skb;
    const ushort_t* bg = B + (size_t)(bn * 128 + srow) * ldb + skb;
    const size_t a64 = (size_t)64 * lda, b64 = (size_t)64 * ldb;

    f32x4 zero = {0.f, 0.f, 0.f, 0.f};
    f32x4 acc[4][4];
#pragma unroll
    for (int m = 0; m < 4; ++m)
#pragma unroll
        for (int n = 0; n < 4; ++n) acc[m][n] = zero;

    f32x4 rs[4];            // MODE 2 rowsums
    short8 ones;
#pragma unroll
    for (int e = 0; e < 8; ++e) ones[e] = (short)0x3F80;   // bf16 1.0
#pragma unroll
    for (int m = 0; m < 4; ++m) rs[m] = zero;

    // prologue: stage ks=0 into buf 0
    gload16(ag, &As[0][tid * 8]);
    gload16(ag + a64, &As[0][tid * 8 + 2048]);
    gload16(bg, &Bs[0][tid * 8]);
    gload16(bg + b64, &Bs[0][tid * 8 + 2048]);
    ag += 32; bg += 32;
    __syncthreads();   // drains vmcnt -> buf0 visible

    int cur = 0;
    for (int ks = 0; ks < nk; ++ks) {
        // stage-ahead: issue next tile's loads first (fly under compute)
        if (ks + 1 < nk) {
            const int nxt = cur ^ 1;
            gload16(ag, &As[nxt][tid * 8]);
            gload16(ag + a64, &As[nxt][tid * 8 + 2048]);
            gload16(bg, &Bs[nxt][tid * 8]);
            gload16(bg + b64, &Bs[nxt][tid * 8 + 2048]);
            ag += 32; bg += 32;
        }

        short8 a[4], b[4];
#pragma unroll
        for (int m = 0; m < 4; ++m)
            a[m] = *(const short8*)&As[cur][(wr + m * 16 + lr) * 32 + kc];
#pragma unroll
        for (int n = 0; n < 4; ++n)
            b[n] = *(const short8*)&Bs[cur][(wc + n * 16 + lr) * 32 + kc];
#pragma unroll
        for (int m = 0; m < 4; ++m)
#pragma unroll
            for (int n = 0; n < 4; ++n)
                acc[m][n] = __builtin_amdgcn_mfma_f32_16x16x32_bf16(a[m], b[n], acc[m][n], 0, 0, 0);
        if constexpr (MODE == 2) {
#pragma unroll
            for (int m = 0; m < 4; ++m)
                rs[m] = __builtin_amdgcn_mfma_f32_16x16x32_bf16(a[m], ones, rs[m], 0, 0, 0);
        }

        __syncthreads();   // drains vmcnt (next buf staged) + seals cur reads
        cur ^= 1;
    }

    const int rbase = (l >> 4) * 4;
    const int cbase = l & 15;

    if constexpr (MODE == 1) {
        ushort_t* C = (ushort_t*)Cbase + (size_t)bz * 2048 * 2048;
#pragma unroll
        for (int m = 0; m < 4; ++m)
#pragma unroll
            for (int n = 0; n < 4; ++n) {
                int gcol = bn * 128 + wc + n * 16 + cbase;
#pragma unroll
                for (int r = 0; r < 4; ++r) {
                    int grow = bm * 128 + wr + m * 16 + rbase + r;
                    ushort_t pv = (gcol <= grow) ? f2bf(__expf(acc[m][n][r] * 0.03125f))
                                                 : (ushort_t)0;
                    C[(size_t)grow * 2048 + gcol] = pv;
                }
            }
    } else {
        float inv[4][4];
#pragma unroll
        for (int m = 0; m < 4; ++m)
#pragma unroll
            for (int r = 0; r < 4; ++r) inv[m][r] = 1.0f / rs[m][r];
        float* C = (float*)Cbase + (size_t)bz * 2048 * 1024;
#pragma unroll
        for (int m = 0; m < 4; ++m)
#pragma unroll
            for (int n = 0; n < 4; ++n) {
                int gcol = bn * 128 + wc + n * 16 + cbase;
#pragma unroll
                for (int r = 0; r < 4; ++r) {
                    int grow = bm * 128 + wr + m * 16 + rbase + r;
                    C[(size_t)grow * 1024 + gcol] = acc[m][n][r] * inv[m][r];
                }
            }
    }
}

extern "C" void kernel_launch(void* const* d_in, const int* in_sizes, int n_in,
                              void* d_out, int out_size, void* d_ws, size_t ws_size,
                              hipStream_t stream) {
    const float* x  = (const float*)d_in[0];
    const float* Wq = (const float*)d_in[1];
    const float* Wk = (const float*)d_in[2];
    const float* Wv = (const float*)d_in[3];

    char* ws = (char*)d_ws;
    ushort_t* xb  = (ushort_t*)(ws);                 // 16 MB [8192][1024]
    ushort_t* Wqb = (ushort_t*)(ws + 16777216);      // 2 MB
    ushort_t* Wkb = (ushort_t*)(ws + 18874368);      // 2 MB
    ushort_t* Mt  = (ushort_t*)(ws + 20971520);      // 2 MB [e][d] = (Wq.Wk^T)^T
    ushort_t* Wvt = (ushort_t*)(ws + 23068672);      // 2 MB (adjacent to Mt)
    ushort_t* y   = (ushort_t*)(ws + 25165824);      // 16 MB [8192][1024] = x.M
    ushort_t* Vt  = (ushort_t*)(ws + 41943040);      // 16 MB [4][1024][2048]
    ushort_t* P   = (ushort_t*)(ws + 58720256);      // 32 MB [4][2048][2048] bf16

    k_prep<<<dim3(32, 32, 4), dim3(32, 8), 0, stream>>>(x, Wq, Wk, Wv, xb, Wqb, Wkb, Wvt);
    k_gemm<3><<<dim3(8, 8), 256, 0, stream>>>(Wkb, Wqb, Mt, nullptr);
    k_gemm<0><<<dim3(64, 8, 2), 256, 0, stream>>>(xb, Mt, y, Vt);
    k_attn<1><<<dim3(136, 1, 4), 256, 0, stream>>>(y, xb, P);
    k_attn<2><<<dim3(16, 8, 4), 256, 0, stream>>>(P, Vt, (float*)d_out);
}